// Round 11
// baseline (603.957 us; speedup 1.0000x reference)
//
#include <hip/hip_runtime.h>

#define IH 512
#define IW 512
#define OH 510
#define OW 510
#define NB 32
#define KO 16
#define OHW (OH * OW)
#define T 8            // tiles per block; 1020 blocks * 8 = 8160 tiles

typedef float f32x4 __attribute__((ext_vector_type(4)));
typedef float f32x2 __attribute__((ext_vector_type(2)));

// R11: counted-vmcnt software pipeline for continuous store flow.
// vmcnt is ONE in-order counter for loads+stores. Therefore:
//   (1) loads of tile t+2 are issued BEFORE stores of tile t -> a wait for
//       load data never forces retirement of younger stores;
//   (2) accumulators are double-buffered (accA/accB, statically named) ->
//       reusing accA at tile t+2 waits only on tile t's stores, which have
//       had a full iteration (~1-2us) to drain. No vmcnt(0) in the loop.
// Result: each wave issues 8 stores every iteration, continuously, like the
// 6.9-TB/s fill kernel -- instead of one burst then death (R9: ~52% duty).
// 512-thr block = 2 row-halves x 2 o-halves (8 filters/thread) to keep
// VGPR ~120 (<=128 cap at 4 waves/SIMD).

struct TP { const float* xr; float* op; };

__device__ __forceinline__ TP tile_ptrs(int tile, int half, int oh, int j,
                                        const float* __restrict__ x,
                                        float* __restrict__ out)
{
    const int n  = tile / 255;
    const int rp = tile - n * 255;
    const int i  = 2 * rp + half;      // i parity == half parity
    TP r;
    r.xr = x + ((size_t)n * IH + i) * IW + j;
    r.op = out + (((size_t)(n * KO + 8 * oh)) * OH + i) * OW + j;
    return r;
}

__device__ __forceinline__ void load_tile(const float* __restrict__ xr,
                                          bool tail, float v[3][6])
{
#pragma unroll
    for (int r = 0; r < 3; ++r) {
        const float2 a = *reinterpret_cast<const float2*>(xr + r * IW);
        const float2 b = *reinterpret_cast<const float2*>(xr + r * IW + 2);
        v[r][0] = a.x; v[r][1] = a.y; v[r][2] = b.x; v[r][3] = b.y;
        if (!tail) {
            const float2 c = *reinterpret_cast<const float2*>(xr + r * IW + 4);
            v[r][4] = c.x; v[r][5] = c.y;
        } else {
            v[r][4] = 0.0f; v[r][5] = 0.0f;
        }
    }
}

__device__ __forceinline__ void fma8(const float xv[3][6],
                                     const float* __restrict__ k, int ob,
                                     float acc[8][4])
{
#pragma unroll
    for (int o = 0; o < 8; ++o) {
        float a0 = 0.f, a1 = 0.f, a2 = 0.f, a3 = 0.f;
#pragma unroll
        for (int r = 0; r < 3; ++r)
#pragma unroll
            for (int c = 0; c < 3; ++c) {
                const float kv = k[((ob + o) * 3 + r) * 3 + c]; // uniform s_load
                a0 = fmaf(xv[r][c],     kv, a0);
                a1 = fmaf(xv[r][c + 1], kv, a1);
                a2 = fmaf(xv[r][c + 2], kv, a2);
                a3 = fmaf(xv[r][c + 3], kv, a3);
            }
        acc[o][0] = a0; acc[o][1] = a1; acc[o][2] = a2; acc[o][3] = a3;
    }
}

__device__ __forceinline__ void store8(const float acc[8][4],
                                       float* __restrict__ op, bool tail)
{
#pragma unroll
    for (int o = 0; o < 8; ++o) {
        float* p = op + (size_t)o * OHW;
        if (!tail) {
            f32x4 v = {acc[o][0], acc[o][1], acc[o][2], acc[o][3]};
            __builtin_nontemporal_store(v, reinterpret_cast<f32x4*>(p));
        } else {
            f32x2 v = {acc[o][0], acc[o][1]};
            __builtin_nontemporal_store(v, reinterpret_cast<f32x2*>(p));
        }
    }
}

__global__ __launch_bounds__(512, 4) void conv3x3_k16_kernel(
    const float* __restrict__ x,
    const float* __restrict__ k,
    float* __restrict__ out)
{
    const int t    = threadIdx.x;
    const int oh   = t >> 8;            // o-half: filters [8*oh, 8*oh+8)
    const int half = (t >> 7) & 1;      // row within pair
    const int tt   = t & 127;
    const bool tail = (tt == 127);

    // Even rows: j=4tt (tail 508); odd rows: j=4tt+2 (tail 0).
    // (i*OW+j)*4 % 16 == 0 for all full threads (row stride 2040B).
    int j;
    if (half == 0) j = tail ? 508 : 4 * tt;
    else           j = tail ? 0   : 4 * tt + 2;

    const int tile0 = blockIdx.x * T;
    const int ob = 8 * oh;

    float xvA[3][6], xvB[3][6], accA[8][4], accB[8][4];

    // Prologue: prefetch tiles 0 and 1 (loads precede all stores).
    TP pA = tile_ptrs(tile0,     half, oh, j, x, out);
    load_tile(pA.xr, tail, xvA);
    TP pB = tile_ptrs(tile0 + 1, half, oh, j, x, out);
    load_tile(pB.xr, tail, xvB);

#pragma unroll 1
    for (int q = 0; q < T; q += 2) {
        // -- even stage: consume A --
        fma8(xvA, k, ob, accA);             // waits only on xvA loads
        float* opA = pA.op;
        if (q + 2 < T) {
            pA = tile_ptrs(tile0 + q + 2, half, oh, j, x, out);
            load_tile(pA.xr, tail, xvA);    // issued BEFORE accA stores
        }
        store8(accA, opA, tail);

        // -- odd stage: consume B --
        fma8(xvB, k, ob, accB);             // waits only on xvB loads
        float* opB = pB.op;
        if (q + 3 < T) {
            pB = tile_ptrs(tile0 + q + 3, half, oh, j, x, out);
            load_tile(pB.xr, tail, xvB);    // issued BEFORE accB stores
        }
        store8(accB, opB, tail);
    }
}

extern "C" void kernel_launch(void* const* d_in, const int* in_sizes, int n_in,
                              void* d_out, int out_size, void* d_ws, size_t ws_size,
                              hipStream_t stream) {
    const float* x   = (const float*)d_in[0];
    const float* ker = (const float*)d_in[1];
    float* out       = (float*)d_out;

    dim3 grid(1020);   // 1020 blocks * T(8) tiles = 8160 = 32 images * 255 pairs
    dim3 block(512);
    conv3x3_k16_kernel<<<grid, block, 0, stream>>>(x, ker, out);
}

// Round 12
// 123.206 us; speedup vs baseline: 4.9020x; 4.9020x over previous
//
#include <hip/hip_runtime.h>

#define IH 512
#define IW 512
#define OH 510
#define OW 510
#define NB 32
#define KO 16
#define OHW (OH * OW)
#define LO 1020            // floats per plane-region in LDS (2 rows x 510)

typedef float f32x4 __attribute__((ext_vector_type(4)));
typedef float f32x2 __attribute__((ext_vector_type(2)));

// R12 = R9 with the store phase bounced through LDS to kill per-wave write
// fan-out (the last untested difference vs the 6.9 TB/s fill / 6.3 TB/s copy
// kernels: our waves interleave 16 write regions ~1MB apart; theirs stream 1).
// Compute phase identical to R9. acc -> LDS [16][1020] (65KB = this block's
// entire output, flat (row,col) linearized). One sync. Store phase: thread t
// streams chunk 4t of each plane region in order -> block writes ONE
// contiguous 4080B window at a time, 16 windows in sequence.
// launch_bounds(256,2): 256-VGPR budget (R11 died of spill at 128; need ~110).
// LDS 65,280B -> 2 blocks/CU.
__global__ __launch_bounds__(256, 2) void conv3x3_k16_kernel(
    const float* __restrict__ x,
    const float* __restrict__ k,
    float* __restrict__ out)
{
    __shared__ float lds[KO * LO];   // 65,280 B

    const int bid = blockIdx.x;
    const int n  = bid / (OH / 2);            // image
    const int i0 = (bid - n * (OH / 2)) * 2;  // even base row
    const int t  = threadIdx.x;
    const int half = t >> 7;                  // row within pair
    const int tt = t & 127;
    const int i  = i0 + half;                 // output row
    const bool tail = (tt == 127);

    // Even rows: j=4tt (tail 508); odd rows: j=4tt+2 (tail 0).
    int j;
    if ((i & 1) == 0) j = tail ? 508 : 4 * tt;
    else              j = tail ? 0   : 4 * tt + 2;

    const float* xr = x + ((size_t)n * IH + i) * IW + j;

    // Phase 1: load 3 rows x 6 cols (tail: 3 x 4), 8B-aligned float2s.
    float xv[3][6];
#pragma unroll
    for (int r = 0; r < 3; ++r) {
        const float2 a = *reinterpret_cast<const float2*>(xr + r * IW);
        const float2 b = *reinterpret_cast<const float2*>(xr + r * IW + 2);
        xv[r][0] = a.x; xv[r][1] = a.y; xv[r][2] = b.x; xv[r][3] = b.y;
        if (!tail) {
            const float2 c = *reinterpret_cast<const float2*>(xr + r * IW + 4);
            xv[r][4] = c.x; xv[r][5] = c.y;
        } else {
            xv[r][4] = 0.0f; xv[r][5] = 0.0f;
        }
    }

    // Phase 2: FMA (identical to R9), deposit into LDS.
    // acc[o][c] = out(row i, col j+c) -> flat f = half*510 + (j+c).
    const int lbase = half * OW + j;          // even -> 8B-aligned f32x2 ok
#pragma unroll
    for (int o = 0; o < KO; ++o) {
        float a0 = 0.f, a1 = 0.f, a2 = 0.f, a3 = 0.f;
#pragma unroll
        for (int r = 0; r < 3; ++r)
#pragma unroll
            for (int c = 0; c < 3; ++c) {
                const float kv = k[(o * 3 + r) * 3 + c];  // uniform -> s_load
                a0 = fmaf(xv[r][c],     kv, a0);
                a1 = fmaf(xv[r][c + 1], kv, a1);
                a2 = fmaf(xv[r][c + 2], kv, a2);
                a3 = fmaf(xv[r][c + 3], kv, a3);
            }
        float* lp = &lds[o * LO + lbase];
        f32x2 v0; v0[0] = a0; v0[1] = a1;
        *reinterpret_cast<f32x2*>(lp) = v0;
        if (!tail) {
            f32x2 v1; v1[0] = a2; v1[1] = a3;
            *reinterpret_cast<f32x2*>(lp + 2) = v1;
        }
    }

    __syncthreads();

    // Phase 3: stream out. Thread t owns flat chunk [4t, 4t+4) of every
    // plane region; global offset for flat f is plane_base + i0*OW + f
    // (rows are adjacent, so (row,col) linearizes). All 16B-aligned:
    // plane stride 1,040,400 % 16 == 0, i0 even -> i0*2040 % 16 == 0.
    if (t < 255) {
        float* ob = out + ((size_t)(n * KO) * OH + i0) * OW;
        const int f = 4 * t;
#pragma unroll
        for (int o = 0; o < KO; ++o) {
            const f32x4 v = *reinterpret_cast<const f32x4*>(&lds[o * LO + f]);
            __builtin_nontemporal_store(v,
                reinterpret_cast<f32x4*>(ob + (size_t)o * OHW + f));
        }
    }
}

extern "C" void kernel_launch(void* const* d_in, const int* in_sizes, int n_in,
                              void* d_out, int out_size, void* d_ws, size_t ws_size,
                              hipStream_t stream) {
    const float* x   = (const float*)d_in[0];
    const float* ker = (const float*)d_in[1];
    float* out       = (float*)d_out;

    dim3 grid(NB * (OH / 2));   // 8160 blocks: (image, row-pair)
    dim3 block(256);
    conv3x3_k16_kernel<<<grid, block, 0, stream>>>(x, ker, out);
}

// Round 13
// 121.649 us; speedup vs baseline: 4.9648x; 1.0128x over previous
//
#include <hip/hip_runtime.h>

#define IH 512
#define IW 512
#define OH 510
#define OW 510
#define NB 32
#define KO 16
#define OHW (OH * OW)
#define PPB 8              // planes per block
#define LO 1020            // floats per plane-region in LDS (2 rows x 510)

typedef float f32x4 __attribute__((ext_vector_type(4)));
typedef float f32x2 __attribute__((ext_vector_type(2)));

// R13 = R12 with half-size LDS tiles (8 planes, 32.6KB) and 2x blocks ->
// 4-5 blocks/CU instead of 2. Theory: R12's residual 38us over the 85us
// write floor is correlated phase gaps (with 2 resident blocks/CU, both are
// often in compute/sync simultaneously -> CU write port idle). More, smaller,
// finer-grained blocks decorrelate the phases and smooth store flow.
// oh is the fastest grid bit so both o-halves of a tile share x rows in L2.
__global__ __launch_bounds__(256, 4) void conv3x3_k16_kernel(
    const float* __restrict__ x,
    const float* __restrict__ k,
    float* __restrict__ out)
{
    __shared__ float lds[PPB * LO];   // 32,640 B

    const int bid  = blockIdx.x;
    const int oh   = bid & 1;                 // filter half: planes 8*oh..
    const int tile = bid >> 1;
    const int n  = tile / (OH / 2);           // image
    const int i0 = (tile - n * (OH / 2)) * 2; // even base row
    const int t  = threadIdx.x;
    const int half = t >> 7;                  // row within pair
    const int tt = t & 127;
    const int i  = i0 + half;                 // output row
    const bool tail = (tt == 127);

    // Even rows: j=4tt (tail 508); odd rows: j=4tt+2 (tail 0).
    int j;
    if ((i & 1) == 0) j = tail ? 508 : 4 * tt;
    else              j = tail ? 0   : 4 * tt + 2;

    const float* xr = x + ((size_t)n * IH + i) * IW + j;

    // Phase 1: load 3 rows x 6 cols (tail: 3 x 4), 8B-aligned float2s.
    float xv[3][6];
#pragma unroll
    for (int r = 0; r < 3; ++r) {
        const float2 a = *reinterpret_cast<const float2*>(xr + r * IW);
        const float2 b = *reinterpret_cast<const float2*>(xr + r * IW + 2);
        xv[r][0] = a.x; xv[r][1] = a.y; xv[r][2] = b.x; xv[r][3] = b.y;
        if (!tail) {
            const float2 c = *reinterpret_cast<const float2*>(xr + r * IW + 4);
            xv[r][4] = c.x; xv[r][5] = c.y;
        } else {
            xv[r][4] = 0.0f; xv[r][5] = 0.0f;
        }
    }

    // Phase 2: FMA for 8 planes, deposit into LDS.
    const int lbase = half * OW + j;
#pragma unroll
    for (int ol = 0; ol < PPB; ++ol) {
        const int o = PPB * oh + ol;
        float a0 = 0.f, a1 = 0.f, a2 = 0.f, a3 = 0.f;
#pragma unroll
        for (int r = 0; r < 3; ++r)
#pragma unroll
            for (int c = 0; c < 3; ++c) {
                const float kv = k[(o * 3 + r) * 3 + c];  // uniform -> s_load
                a0 = fmaf(xv[r][c],     kv, a0);
                a1 = fmaf(xv[r][c + 1], kv, a1);
                a2 = fmaf(xv[r][c + 2], kv, a2);
                a3 = fmaf(xv[r][c + 3], kv, a3);
            }
        float* lp = &lds[ol * LO + lbase];
        f32x2 v0; v0[0] = a0; v0[1] = a1;
        *reinterpret_cast<f32x2*>(lp) = v0;
        if (!tail) {
            f32x2 v1; v1[0] = a2; v1[1] = a3;
            *reinterpret_cast<f32x2*>(lp + 2) = v1;
        }
    }

    __syncthreads();

    // Phase 3: stream out. Thread t owns flat chunk [4t,4t+4) of each of the
    // 8 plane regions; block writes one contiguous 4080B window at a time.
    // Alignment: plane stride 1,040,400 % 16 == 0; i0 even -> i0*2040 % 16 == 0.
    if (t < 255) {
        float* ob = out + (((size_t)(n * KO + PPB * oh)) * OH + i0) * OW;
        const int f = 4 * t;
#pragma unroll
        for (int ol = 0; ol < PPB; ++ol) {
            const f32x4 v = *reinterpret_cast<const f32x4*>(&lds[ol * LO + f]);
            __builtin_nontemporal_store(v,
                reinterpret_cast<f32x4*>(ob + (size_t)ol * OHW + f));
        }
    }
}

extern "C" void kernel_launch(void* const* d_in, const int* in_sizes, int n_in,
                              void* d_out, int out_size, void* d_ws, size_t ws_size,
                              hipStream_t stream) {
    const float* x   = (const float*)d_in[0];
    const float* ker = (const float*)d_in[1];
    float* out       = (float*)d_out;

    dim3 grid(NB * (OH / 2) * 2);   // 16320 blocks: (image, row-pair) x o-half
    dim3 block(256);
    conv3x3_k16_kernel<<<grid, block, 0, stream>>>(x, ker, out);
}